// Round 6
// baseline (182.107 us; speedup 1.0000x reference)
//
#include <hip/hip_runtime.h>
#include <cfloat>

typedef short bf16x8 __attribute__((ext_vector_type(8)));
typedef float f32x4  __attribute__((ext_vector_type(4)));

static __device__ __forceinline__ unsigned int pack2(float a, float b) {
    unsigned short ha = __builtin_bit_cast(unsigned short, (__bf16)a);
    unsigned short hb = __builtin_bit_cast(unsigned short, (__bf16)b);
    return (unsigned int)ha | ((unsigned int)hb << 16);
}

// ---------------- kernel 1: prep ----------------
// blocks 0..63    : W -> bf16 LINEAR wh + ||w||^2   (no swizzle: no LDS path)
// blocks 64..1087 : X -> token-major bf16 LINEAR Xt (batch-load 32 channels
//                   into registers for ILP; 64B contiguous store/thread) +
//                   per-wave sum x^2 -> DISTINCT slot (non-atomic; no zeroing)
__global__ __launch_bounds__(256) void prep_kernel(
    const float* __restrict__ W, const float* __restrict__ X,
    unsigned short* __restrict__ wh, float* __restrict__ cw,
    unsigned short* __restrict__ xt, float* __restrict__ xsq)
{
    int t = threadIdx.x, blk = blockIdx.x;
    if (blk < 64) {
        int row = blk * 16 + (t >> 4);
        int c0  = (t & 15) * 16;
        const float* wr = W + row * 256 + c0;
        float s = 0.f;
        unsigned int pk[8];
#pragma unroll
        for (int i = 0; i < 16; i += 2) {
            float a = wr[i], b = wr[i + 1];
            s += a * a + b * b;
            pk[i >> 1] = pack2(a, b);
        }
        uint4* dst = (uint4*)&wh[row * 256 + c0];
        dst[0] = make_uint4(pk[0], pk[1], pk[2], pk[3]);
        dst[1] = make_uint4(pk[4], pk[5], pk[6], pk[7]);
#pragma unroll
        for (int m = 1; m < 16; m <<= 1) s += __shfl_xor(s, m, 64);
        if ((t & 15) == 0) cw[row] = s;
    } else {
        int bx = blk - 64;                        // 0..1023
        int er = bx >> 7;                         // channel-eighth, uniform per block
        int tok = (bx & 127) * 256 + t;           // lanes = consecutive tokens
        int b = tok >> 10, s = tok & 1023;
        const float* xp = X + ((size_t)b << 18) + s + ((size_t)(er * 32) << 10);

        float va[32];                             // all 32 loads in flight first
#pragma unroll
        for (int i = 0; i < 32; ++i) va[i] = xp[(size_t)i << 10];

        float acc = 0.f;
        unsigned int pk[16];
#pragma unroll
        for (int i = 0; i < 32; i += 2) {
            acc = fmaf(va[i], va[i], fmaf(va[i + 1], va[i + 1], acc));
            pk[i >> 1] = pack2(va[i], va[i + 1]);
        }
        uint4* dst = (uint4*)&xt[(size_t)tok * 256];
#pragma unroll
        for (int g = 0; g < 4; ++g)
            dst[er * 4 + g] = make_uint4(pk[g*4], pk[g*4+1], pk[g*4+2], pk[g*4+3]);

#pragma unroll
        for (int m = 1; m < 64; m <<= 1) acc += __shfl_xor(acc, m, 64);
        if ((t & 63) == 0) xsq[bx * 4 + (t >> 6)] = acc;   // plain store, unique slot
    }
}

// ---------------- kernel 2: LDS-free distance-GEMM + per-quarter argmin ----
// grid 256 = 64 token-groups x 4 code-quarters; block 512thr (8 waves).
// W fragments streamed global->register (L2-resident, 64B-sector-perfect),
// named A/B register double-buffer. X fragments resident in registers.
// No LDS, no barriers, no atomics.
__global__ __launch_bounds__(512) void argmin_kernel(
    const unsigned short* __restrict__ wh, const unsigned short* __restrict__ xt,
    const float* __restrict__ cw, float2* __restrict__ partial)
{
    int tid  = threadIdx.x;
    int lane = tid & 63, w = tid >> 6;
    int g = blockIdx.x >> 2, q = blockIdx.x & 3;
    int srow = lane & 15, kgrp = lane >> 4;

    const unsigned short* whq = wh + (size_t)q * 256 * 256;   // this quarter's 256 codes

    // X fragments: 32 x b128 in flight
    int T0 = g * 512 + w * 64;
    bf16x8 fx[4][8];
#pragma unroll
    for (int tt = 0; tt < 4; ++tt) {
        const unsigned short* xr = xt + (size_t)(T0 + tt * 16 + srow) * 256;
#pragma unroll
        for (int ks = 0; ks < 8; ++ks)
            fx[tt][ks] = *(const bf16x8*)&xr[(ks * 4 + kgrp) * 8];
    }

    float best[4] = {FLT_MAX, FLT_MAX, FLT_MAX, FLT_MAX};
    int   bidx[4] = {0, 0, 0, 0};
    const float* cwq = cw + q * 256;

    bf16x8 afA[8], afB[8];
    auto loadAF = [&](bf16x8* dst, int ch) {
        const unsigned short* ar = whq + (size_t)(ch * 16 + srow) * 256;
#pragma unroll
        for (int ks = 0; ks < 8; ++ks)
            dst[ks] = *(const bf16x8*)&ar[(ks * 4 + kgrp) * 8];
    };
    auto compute = [&](const bf16x8* af, int ch) {
        float4 cw4 = *(const float4*)&cwq[ch * 16 + kgrp * 4];
        f32x4 acc[4];
#pragma unroll
        for (int tt = 0; tt < 4; ++tt) acc[tt] = (f32x4){0.f, 0.f, 0.f, 0.f};
#pragma unroll
        for (int ks = 0; ks < 8; ++ks)
#pragma unroll
            for (int tt = 0; tt < 4; ++tt)
                acc[tt] = __builtin_amdgcn_mfma_f32_16x16x32_bf16(
                    af[ks], fx[tt][ks], acc[tt], 0, 0, 0);
        int cb = q * 256 + ch * 16 + kgrp * 4;
#pragma unroll
        for (int j = 0; j < 4; ++j) {
            float cwv = j == 0 ? cw4.x : j == 1 ? cw4.y : j == 2 ? cw4.z : cw4.w;
#pragma unroll
            for (int tt = 0; tt < 4; ++tt) {
                float e2 = fmaf(-2.f, acc[tt][j], cwv);
                bool better = e2 < best[tt];       // strict <: lowest code wins
                best[tt] = better ? e2 : best[tt];
                bidx[tt] = better ? (cb + j) : bidx[tt];
            }
        }
    };

    loadAF(afA, 0);
#pragma unroll
    for (int ch = 0; ch < 16; ch += 2) {
        loadAF(afB, ch + 1);                       // prefetch odd chunk
        compute(afA, ch);
        if (ch + 2 < 16) loadAF(afA, ch + 2);      // prefetch next even chunk
        compute(afB, ch + 1);
    }

    // in-wave argmin over kgrp groups, then per-quarter partial to global
#pragma unroll
    for (int tt = 0; tt < 4; ++tt) {
        float v = best[tt]; int id = bidx[tt];
#pragma unroll
        for (int m = 16; m <= 32; m <<= 1) {
            float ve = __shfl_xor(v, m, 64);
            int   ie = __shfl_xor(id, m, 64);
            if (ve < v || (ve == v && ie < id)) { v = ve; id = ie; }
        }
        if (lane < 16)
            partial[(size_t)q * 32768 + T0 + tt * 16 + lane] =
                make_float2(v, __int_as_float(id));
    }
}

// ---------------- kernel 3: combine quarters + gather + NCHW store + losses ----
__global__ __launch_bounds__(256) void out_kernel(
    const float* __restrict__ W, const float2* __restrict__ partial,
    const float* __restrict__ xsq, float* __restrict__ dsum,
    unsigned int* __restrict__ counter, float* __restrict__ out)
{
    __shared__ float tile[256][65];
    __shared__ int lidx[64];
    __shared__ int elected;
    int t = threadIdx.x, g = blockIdx.x;
    int n0 = g * 64;
    int b = n0 >> 10, sb = n0 & 1023;

    if (t == 0) elected = 0;
    if (t < 64) {
        float2 p = partial[n0 + t];
        float v = p.x; int id = __float_as_int(p.y);
#pragma unroll
        for (int q = 1; q < 4; ++q) {
            float2 pq = partial[(size_t)q * 32768 + n0 + t];
            if (pq.x < v) { v = pq.x; id = __float_as_int(pq.y); }  // tie -> lower q
        }
        lidx[t] = id;
        float dmin = v;                            // min(-2x.w + ||w||^2) part only
#pragma unroll
        for (int m = 1; m < 64; m <<= 1) dmin += __shfl_xor(dmin, m, 64);
        if (t == 0) {
            dsum[g] = dmin;                        // plain store, unique slot
            __threadfence();
            // poison-tolerant election: exactly one block sees old % 512 == 511
            if ((atomicAdd(counter, 1u) & 511u) == 511u) elected = 1;
        }
    }
    __syncthreads();

    int tok = t >> 2, cq = t & 3;
    const float* wr = W + ((size_t)lidx[tok] << 8);
#pragma unroll
    for (int j = 0; j < 16; ++j) {
        int c = cq * 4 + j * 16;
        float4 v = *(const float4*)&wr[c];
        tile[c + 0][tok] = v.x; tile[c + 1][tok] = v.y;
        tile[c + 2][tok] = v.z; tile[c + 3][tok] = v.w;
    }
    __syncthreads();
    float* op = out + (((size_t)(b * 256 + t)) << 10) + sb;
#pragma unroll
    for (int j = 0; j < 16; ++j) {
        float4 v;
        v.x = tile[t][j * 4 + 0]; v.y = tile[t][j * 4 + 1];
        v.z = tile[t][j * 4 + 2]; v.w = tile[t][j * 4 + 3];
        *(float4*)&op[j * 4] = v;
    }

    if (elected && t < 64) {                       // wave-parallel finalize
        __threadfence();                           // acquire all dsum/xsq stores
        float acc = 0.f;
        for (int i = t; i < 4096; i += 64) acc += xsq[i];
        for (int i = t; i < 512;  i += 64) acc += dsum[i];
#pragma unroll
        for (int m = 1; m < 64; m <<= 1) acc += __shfl_xor(acc, m, 64);
        if (t == 0) {
            float mse = acc * (1.0f / 8388608.0f);
            out[8388608] = 1.25f * mse;            // vq_loss
            out[8388609] = mse;                    // embedding_loss
            out[8388610] = mse;                    // commitment_loss
        }
    }
}

extern "C" void kernel_launch(void* const* d_in, const int* in_sizes, int n_in,
                              void* d_out, int out_size, void* d_ws, size_t ws_size,
                              hipStream_t stream)
{
    (void)in_sizes; (void)n_in; (void)out_size; (void)ws_size;
    const float* X = (const float*)d_in[0];   // [32,256,32,32] fp32
    const float* W = (const float*)d_in[1];   // [1024,256] fp32
    float* out = (float*)d_out;               // [8388608 out | vq | emb | commit]
    char* ws = (char*)d_ws;
    unsigned int*   counter = (unsigned int*)ws;                 // @0 (poison-tolerant)
    float*          cw      = (float*)(ws + 4096);               // 4KB
    unsigned short* wh      = (unsigned short*)(ws + 8192);      // 512KB (LINEAR bf16)
    float*          xsq     = (float*)(ws + 1048576);            // 16KB (4096 slots)
    float*          dsum    = (float*)(ws + 1114112);            // 2KB  (512 slots)
    unsigned short* xt      = (unsigned short*)(ws + 2097152);   // 16.8MB (linear bf16)
    float2*         partial = (float2*)(ws + 19922944);          // 1MB

    prep_kernel<<<1088, 256, 0, stream>>>(W, X, wh, cw, xt, xsq);
    argmin_kernel<<<256, 512, 0, stream>>>(wh, xt, cw, partial);
    out_kernel<<<512, 256, 0, stream>>>(W, partial, xsq, dsum, counter, out);
}

// Round 7
// 100.356 us; speedup vs baseline: 1.8146x; 1.8146x over previous
//
#include <hip/hip_runtime.h>
#include <cfloat>

typedef short bf16x8 __attribute__((ext_vector_type(8)));
typedef float f32x4  __attribute__((ext_vector_type(4)));

static __device__ __forceinline__ void gl_lds16(const void* g, void* l) {
    __builtin_amdgcn_global_load_lds(
        (const __attribute__((address_space(1))) unsigned int*)g,
        (__attribute__((address_space(3))) unsigned int*)l, 16, 0, 0);
}

static __device__ __forceinline__ unsigned int pack2(float a, float b) {
    unsigned short ha = __builtin_bit_cast(unsigned short, (__bf16)a);
    unsigned short hb = __builtin_bit_cast(unsigned short, (__bf16)b);
    return (unsigned int)ha | ((unsigned int)hb << 16);
}

// ---------------- kernel 1: prep ----------------
// blocks 0..63    : W -> bf16 XOR-swizzled wh (16B granule ^ (row&7)) + ||w||^2
// blocks 64..1087 : X -> token-major bf16 LINEAR Xt (32-channel register batch
//                   for ILP, 64B contiguous store) + per-wave sum x^2 to a
//                   DISTINCT slot (non-atomic, rewritten every call)
__global__ __launch_bounds__(256) void prep_kernel(
    const float* __restrict__ W, const float* __restrict__ X,
    unsigned short* __restrict__ wh, float* __restrict__ cw,
    unsigned short* __restrict__ xt, float* __restrict__ xsq)
{
    int t = threadIdx.x, blk = blockIdx.x;
    if (blk < 64) {
        int row = blk * 16 + (t >> 4);
        int c0  = (t & 15) * 16;
        const float* wr = W + row * 256 + c0;
        float s = 0.f;
        unsigned int pk[8];
#pragma unroll
        for (int i = 0; i < 16; i += 2) {
            float a = wr[i], b = wr[i + 1];
            s += a * a + b * b;
            pk[i >> 1] = pack2(a, b);
        }
        int g0 = (t & 15) * 2, e = row & 7;        // swizzle for the LDS read path
        uint4* dst = (uint4*)&wh[row * 256];
        dst[g0 ^ e]       = make_uint4(pk[0], pk[1], pk[2], pk[3]);
        dst[(g0 + 1) ^ e] = make_uint4(pk[4], pk[5], pk[6], pk[7]);
#pragma unroll
        for (int m = 1; m < 16; m <<= 1) s += __shfl_xor(s, m, 64);
        if ((t & 15) == 0) cw[row] = s;
    } else {
        int bx = blk - 64;                          // 0..1023
        int er = bx >> 7;                           // channel-eighth, uniform per block
        int tok = (bx & 127) * 256 + t;             // lanes = consecutive tokens
        int b = tok >> 10, s = tok & 1023;
        const float* xp = X + ((size_t)b << 18) + s + ((size_t)(er * 32) << 10);

        float va[32];                               // all 32 loads in flight first
#pragma unroll
        for (int i = 0; i < 32; ++i) va[i] = xp[(size_t)i << 10];

        float acc = 0.f;
        unsigned int pk[16];
#pragma unroll
        for (int i = 0; i < 32; i += 2) {
            acc = fmaf(va[i], va[i], fmaf(va[i + 1], va[i + 1], acc));
            pk[i >> 1] = pack2(va[i], va[i + 1]);
        }
        uint4* dst = (uint4*)&xt[(size_t)tok * 256];
#pragma unroll
        for (int g = 0; g < 4; ++g)
            dst[er * 4 + g] = make_uint4(pk[g*4], pk[g*4+1], pk[g*4+2], pk[g*4+3]);

#pragma unroll
        for (int m = 1; m < 64; m <<= 1) acc += __shfl_xor(acc, m, 64);
        if ((t & 63) == 0) xsq[bx * 4 + (t >> 6)] = acc;   // unique slot, no atomic
    }
}

// ---------------- kernel 2: distance-GEMM + per-sixteenth argmin ----------------
// grid 4096 = 256 token-subgroups (fast) x 16 code-sixteenths (slow);
// block 128 thr (2 waves) + 32KB LDS (64 codes) -> 4 blocks/CU resident,
// 16 blocks/CU queued: ramps overlap other blocks' compute, no cross-block
// coupling. Wave = 64 tokens (fx[4][8] resident). launch_bounds(128,2) ->
// 256-VGPR budget, no spill (R6 lesson).
__global__ __launch_bounds__(128, 2) void argmin_kernel(
    const unsigned short* __restrict__ wh, const unsigned short* __restrict__ xt,
    const float* __restrict__ cw, float2* __restrict__ partial)
{
    __shared__ unsigned short wlds[64 * 256];       // 32 KB
    int tid  = threadIdx.x;
    int lane = tid & 63, w = tid >> 6;              // 2 waves
    int sg  = blockIdx.x & 255;                     // token subgroup (128 tokens)
    int q16 = blockIdx.x >> 8;                      // code sixteenth (64 codes)
    int srow = lane & 15, kgrp = lane >> 4;

    // stage 64 codes x 512B = 32KB; wave w copies granules [w*64 + j*128 + lane]
    const char* wsrc = (const char*)wh + (size_t)q16 * 64 * 512 + w * 1024;
    char* ldst = (char*)wlds + w * 1024;
#pragma unroll
    for (int j = 0; j < 16; ++j)
        gl_lds16(wsrc + j * 2048 + lane * 16, ldst + j * 2048);

    // X fragments (overlap with W DMA); Xt linear: granule = ks*4+kgrp
    int T0 = sg * 128 + w * 64;
    bf16x8 fx[4][8];
#pragma unroll
    for (int tt = 0; tt < 4; ++tt) {
        const unsigned short* xr = xt + (size_t)(T0 + tt * 16 + srow) * 256;
#pragma unroll
        for (int ks = 0; ks < 8; ++ks)
            fx[tt][ks] = *(const bf16x8*)&xr[(ks * 4 + kgrp) * 8];
    }
    asm volatile("s_waitcnt vmcnt(0)" ::: "memory"); // own DMA + fx landed
    __syncthreads();                                 // both waves' halves visible

    float best[4] = {FLT_MAX, FLT_MAX, FLT_MAX, FLT_MAX};
    int   bidx[4] = {0, 0, 0, 0};
    const float* cwq = cw + q16 * 64;

#pragma unroll
    for (int ch = 0; ch < 4; ++ch) {
        int r = ch * 16 + srow, eb = r & 7;
        const unsigned short* ar = &wlds[r * 256];
        bf16x8 af[8];
#pragma unroll
        for (int ks = 0; ks < 8; ++ks)
            af[ks] = *(const bf16x8*)&ar[((ks * 4 + kgrp) ^ eb) * 8];

        float4 cw4 = *(const float4*)&cwq[ch * 16 + kgrp * 4];

        f32x4 acc[4];
#pragma unroll
        for (int tt = 0; tt < 4; ++tt) acc[tt] = (f32x4){0.f, 0.f, 0.f, 0.f};
#pragma unroll
        for (int ks = 0; ks < 8; ++ks)
#pragma unroll
            for (int tt = 0; tt < 4; ++tt)
                acc[tt] = __builtin_amdgcn_mfma_f32_16x16x32_bf16(
                    af[ks], fx[tt][ks], acc[tt], 0, 0, 0);

        int cb = q16 * 64 + ch * 16 + kgrp * 4;
#pragma unroll
        for (int j = 0; j < 4; ++j) {
            float cwv = j == 0 ? cw4.x : j == 1 ? cw4.y : j == 2 ? cw4.z : cw4.w;
#pragma unroll
            for (int tt = 0; tt < 4; ++tt) {
                float e2 = fmaf(-2.f, acc[tt][j], cwv);
                bool better = e2 < best[tt];         // strict <: lowest code wins
                best[tt] = better ? e2 : best[tt];
                bidx[tt] = better ? (cb + j) : bidx[tt];
            }
        }
    }

    // in-wave argmin over kgrp groups, then per-sixteenth partial to global
#pragma unroll
    for (int tt = 0; tt < 4; ++tt) {
        float v = best[tt]; int id = bidx[tt];
#pragma unroll
        for (int m = 16; m <= 32; m <<= 1) {
            float ve = __shfl_xor(v, m, 64);
            int   ie = __shfl_xor(id, m, 64);
            if (ve < v || (ve == v && ie < id)) { v = ve; id = ie; }
        }
        if (lane < 16)
            partial[(size_t)q16 * 32768 + T0 + tt * 16 + lane] =
                make_float2(v, __int_as_float(id));
    }
}

// ---------------- kernel 3: combine 16 + gather + NCHW store + losses ----------
__global__ __launch_bounds__(256) void out_kernel(
    const float* __restrict__ W, const float2* __restrict__ partial,
    const float* __restrict__ xsq, float* __restrict__ dsum,
    unsigned int* __restrict__ counter, float* __restrict__ out)
{
    __shared__ float tile[256][65];
    __shared__ int lidx[64];
    __shared__ int elected;
    int t = threadIdx.x, g = blockIdx.x;
    int n0 = g * 64;
    int b = n0 >> 10, sb = n0 & 1023;

    if (t == 0) elected = 0;
    if (t < 64) {
        float2 p = partial[n0 + t];
        float v = p.x; int id = __float_as_int(p.y);
#pragma unroll
        for (int q = 1; q < 16; ++q) {
            float2 pq = partial[(size_t)q * 32768 + n0 + t];
            if (pq.x < v) { v = pq.x; id = __float_as_int(pq.y); }  // tie -> lower q
        }
        lidx[t] = id;
        float dmin = v;                              // min(-2x.w + ||w||^2) part
#pragma unroll
        for (int m = 1; m < 64; m <<= 1) dmin += __shfl_xor(dmin, m, 64);
        if (t == 0) {
            dsum[g] = dmin;                          // plain store, unique slot
            __threadfence();
            // poison-tolerant election: exactly one of 512 sees old % 512 == 511
            if ((atomicAdd(counter, 1u) & 511u) == 511u) elected = 1;
        }
    }
    __syncthreads();

    int tok = t >> 2, cq = t & 3;
    const float* wr = W + ((size_t)lidx[tok] << 8);
#pragma unroll
    for (int j = 0; j < 16; ++j) {
        int c = cq * 4 + j * 16;
        float4 v = *(const float4*)&wr[c];
        tile[c + 0][tok] = v.x; tile[c + 1][tok] = v.y;
        tile[c + 2][tok] = v.z; tile[c + 3][tok] = v.w;
    }
    __syncthreads();
    float* op = out + (((size_t)(b * 256 + t)) << 10) + sb;
#pragma unroll
    for (int j = 0; j < 16; ++j) {
        float4 v;
        v.x = tile[t][j * 4 + 0]; v.y = tile[t][j * 4 + 1];
        v.z = tile[t][j * 4 + 2]; v.w = tile[t][j * 4 + 3];
        *(float4*)&op[j * 4] = v;
    }

    if (elected && t < 64) {                         // wave-parallel finalize
        __threadfence();                             // acquire dsum/xsq stores
        float acc = 0.f;
        for (int i = t; i < 4096; i += 64) acc += xsq[i];
        for (int i = t; i < 512;  i += 64) acc += dsum[i];
#pragma unroll
        for (int m = 1; m < 64; m <<= 1) acc += __shfl_xor(acc, m, 64);
        if (t == 0) {
            float mse = acc * (1.0f / 8388608.0f);
            out[8388608] = 1.25f * mse;              // vq_loss
            out[8388609] = mse;                      // embedding_loss
            out[8388610] = mse;                      // commitment_loss
        }
    }
}

extern "C" void kernel_launch(void* const* d_in, const int* in_sizes, int n_in,
                              void* d_out, int out_size, void* d_ws, size_t ws_size,
                              hipStream_t stream)
{
    (void)in_sizes; (void)n_in; (void)out_size; (void)ws_size;
    const float* X = (const float*)d_in[0];   // [32,256,32,32] fp32
    const float* W = (const float*)d_in[1];   // [1024,256] fp32
    float* out = (float*)d_out;               // [8388608 out | vq | emb | commit]
    char* ws = (char*)d_ws;
    unsigned int*   counter = (unsigned int*)ws;                 // @0 (poison-tolerant)
    float*          cw      = (float*)(ws + 4096);               // 4KB
    unsigned short* wh      = (unsigned short*)(ws + 8192);      // 512KB (swizzled bf16)
    float*          xsq     = (float*)(ws + 1048576);            // 16KB (4096 slots)
    float*          dsum    = (float*)(ws + 1114112);            // 2KB  (512 slots)
    unsigned short* xt      = (unsigned short*)(ws + 2097152);   // 16.8MB (linear bf16)
    float2*         partial = (float2*)(ws + 19922944);          // 4MB (16 x 32768)

    prep_kernel<<<1088, 256, 0, stream>>>(W, X, wh, cw, xt, xsq);
    argmin_kernel<<<4096, 128, 0, stream>>>(wh, xt, cw, partial);
    out_kernel<<<512, 256, 0, stream>>>(W, partial, xsq, dsum, counter, out);
}

// Round 8
// 85.141 us; speedup vs baseline: 2.1389x; 1.1787x over previous
//
#include <hip/hip_runtime.h>
#include <cfloat>

typedef short bf16x8 __attribute__((ext_vector_type(8)));
typedef float f32x4  __attribute__((ext_vector_type(4)));

static __device__ __forceinline__ void gl_lds16(const void* g, void* l) {
    __builtin_amdgcn_global_load_lds(
        (const __attribute__((address_space(1))) unsigned int*)g,
        (__attribute__((address_space(3))) unsigned int*)l, 16, 0, 0);
}

static __device__ __forceinline__ unsigned int pack2(float a, float b) {
    unsigned short ha = __builtin_bit_cast(unsigned short, (__bf16)a);
    unsigned short hb = __builtin_bit_cast(unsigned short, (__bf16)b);
    return (unsigned int)ha | ((unsigned int)hb << 16);
}

// ---------------- kernel 1: prep ----------------
// blocks 0..63    : W -> bf16 XOR-swizzled wh (16B granule ^ (row&7)) + ||w||^2
// blocks 64..1087 : X -> token-major bf16 LINEAR Xt (32-channel register batch
//                   for ILP, 64B contiguous store) + per-wave sum x^2 to a
//                   DISTINCT slot (non-atomic, rewritten every call)
__global__ __launch_bounds__(256) void prep_kernel(
    const float* __restrict__ W, const float* __restrict__ X,
    unsigned short* __restrict__ wh, float* __restrict__ cw,
    unsigned short* __restrict__ xt, float* __restrict__ xsq)
{
    int t = threadIdx.x, blk = blockIdx.x;
    if (blk < 64) {
        int row = blk * 16 + (t >> 4);
        int c0  = (t & 15) * 16;
        const float* wr = W + row * 256 + c0;
        float s = 0.f;
        unsigned int pk[8];
#pragma unroll
        for (int i = 0; i < 16; i += 2) {
            float a = wr[i], b = wr[i + 1];
            s += a * a + b * b;
            pk[i >> 1] = pack2(a, b);
        }
        int g0 = (t & 15) * 2, e = row & 7;        // swizzle for the LDS read path
        uint4* dst = (uint4*)&wh[row * 256];
        dst[g0 ^ e]       = make_uint4(pk[0], pk[1], pk[2], pk[3]);
        dst[(g0 + 1) ^ e] = make_uint4(pk[4], pk[5], pk[6], pk[7]);
#pragma unroll
        for (int m = 1; m < 16; m <<= 1) s += __shfl_xor(s, m, 64);
        if ((t & 15) == 0) cw[row] = s;
    } else {
        int bx = blk - 64;                          // 0..1023
        int er = bx >> 7;                           // channel-eighth, uniform per block
        int tok = (bx & 127) * 256 + t;             // lanes = consecutive tokens
        int b = tok >> 10, s = tok & 1023;
        const float* xp = X + ((size_t)b << 18) + s + ((size_t)(er * 32) << 10);

        float va[32];                               // all 32 loads in flight first
#pragma unroll
        for (int i = 0; i < 32; ++i) va[i] = xp[(size_t)i << 10];

        float acc = 0.f;
        unsigned int pk[16];
#pragma unroll
        for (int i = 0; i < 32; i += 2) {
            acc = fmaf(va[i], va[i], fmaf(va[i + 1], va[i + 1], acc));
            pk[i >> 1] = pack2(va[i], va[i + 1]);
        }
        uint4* dst = (uint4*)&xt[(size_t)tok * 256];
#pragma unroll
        for (int g = 0; g < 4; ++g)
            dst[er * 4 + g] = make_uint4(pk[g*4], pk[g*4+1], pk[g*4+2], pk[g*4+3]);

#pragma unroll
        for (int m = 1; m < 64; m <<= 1) acc += __shfl_xor(acc, m, 64);
        if ((t & 63) == 0) xsq[bx * 4 + (t >> 6)] = acc;   // unique slot, no atomic
    }
}

// ---------------- kernel 2: streamed distance-GEMM + per-quarter argmin -------
// grid 2048 = 512 token-subgroups (fast; same-sg quarters land on same XCD) x
// 4 code-quarters. Block 128thr (2 waves), LDS 2x16KB dbuf -> 4 blocks/CU,
// 16 waves/CU. Wave = 32 tokens; fx[2][8] (64 VGPR) loaded once and PINNED via
// asm so the compiler cannot sink/remat the X loads (R7 lesson: VGPR=100 <
// fx size proved fragments were not register-resident). W quarter streamed as
// 8 chunks x 32 codes via global_load_lds with per-chunk vmcnt+barrier.
__global__ __launch_bounds__(128, 2) void argmin_kernel(
    const unsigned short* __restrict__ wh, const unsigned short* __restrict__ xt,
    const float* __restrict__ cw, float2* __restrict__ partial)
{
    __shared__ __align__(16) unsigned short wlds[2][32 * 256];   // 2 x 16 KB
    int tid  = threadIdx.x;
    int lane = tid & 63, w = tid >> 6;              // 2 waves
    int sg = blockIdx.x & 511;                      // token subgroup (64 tokens)
    int q  = blockIdx.x >> 9;                       // code quarter (256 codes)
    int srow = lane & 15, kgrp = lane >> 4;

    const char* wq = (const char*)wh + (size_t)q * 256 * 512;
    int rsub = w * 2 + (lane >> 5);                 // row within a 4-row DMA round
    int gcol = lane & 31;                           // 16B granule within 512B row

    // stage chunk ch (32 codes x 512B = 16KB) into wlds[buf]
    auto stage = [&](int ch, int buf) {
        const char* src = wq + (size_t)(ch * 32 + rsub) * 512 + gcol * 16;
        char* dstb = (char*)&wlds[buf][0] + w * 1024;   // wave-uniform base
#pragma unroll
        for (int i = 0; i < 8; ++i)
            gl_lds16(src + i * 2048, dstb + i * 2048);
    };

    stage(0, 0);

    // X fragments: 16 x b128 in flight, then PINNED in registers
    int T0 = sg * 64 + w * 32;
    bf16x8 fx[2][8];
#pragma unroll
    for (int tt = 0; tt < 2; ++tt) {
        const unsigned short* xr = xt + (size_t)(T0 + tt * 16 + srow) * 256;
#pragma unroll
        for (int ks = 0; ks < 8; ++ks)
            fx[tt][ks] = *(const bf16x8*)&xr[(ks * 4 + kgrp) * 8];
    }
#pragma unroll
    for (int tt = 0; tt < 2; ++tt)
#pragma unroll
        for (int ks = 0; ks < 8; ++ks)
            asm volatile("" : "+v"(fx[tt][ks]));    // force register residency

    asm volatile("s_waitcnt vmcnt(0)" ::: "memory");
    __syncthreads();                                // chunk 0 + fx visible

    float best[2] = {FLT_MAX, FLT_MAX};
    int   bidx[2] = {0, 0};
    const float* cwq = cw + q * 256;
    int cur = 0;

    for (int ch = 0; ch < 8; ++ch) {
        if (ch < 7) stage(ch + 1, cur ^ 1);         // prefetch overlaps compute

        bf16x8 af[2][8];
#pragma unroll
        for (int rt = 0; rt < 2; ++rt) {
            int r = rt * 16 + srow, eb = r & 7;
            const unsigned short* ar = &wlds[cur][r * 256];
#pragma unroll
            for (int ks = 0; ks < 8; ++ks)
                af[rt][ks] = *(const bf16x8*)&ar[((ks * 4 + kgrp) ^ eb) * 8];
        }

        f32x4 acc[2][2];
#pragma unroll
        for (int rt = 0; rt < 2; ++rt)
#pragma unroll
            for (int tt = 0; tt < 2; ++tt)
                acc[rt][tt] = (f32x4){0.f, 0.f, 0.f, 0.f};
#pragma unroll
        for (int ks = 0; ks < 8; ++ks)
#pragma unroll
            for (int rt = 0; rt < 2; ++rt)
#pragma unroll
                for (int tt = 0; tt < 2; ++tt)
                    acc[rt][tt] = __builtin_amdgcn_mfma_f32_16x16x32_bf16(
                        af[rt][ks], fx[tt][ks], acc[rt][tt], 0, 0, 0);

#pragma unroll
        for (int rt = 0; rt < 2; ++rt) {
            float4 cw4 = *(const float4*)&cwq[ch * 32 + rt * 16 + kgrp * 4];
            int cb = q * 256 + ch * 32 + rt * 16 + kgrp * 4;
#pragma unroll
            for (int j = 0; j < 4; ++j) {
                float cwv = j == 0 ? cw4.x : j == 1 ? cw4.y : j == 2 ? cw4.z : cw4.w;
#pragma unroll
                for (int tt = 0; tt < 2; ++tt) {
                    float e2 = fmaf(-2.f, acc[rt][tt][j], cwv);
                    bool better = e2 < best[tt];     // strict <: lowest code wins
                    best[tt] = better ? e2 : best[tt];
                    bidx[tt] = better ? (cb + j) : bidx[tt];
                }
            }
        }

        asm volatile("s_waitcnt vmcnt(0)" ::: "memory");  // own next-chunk DMA done
        __syncthreads();                                  // all waves' DMA + reads done
        cur ^= 1;
    }

    // in-wave argmin over kgrp groups, then per-quarter partial to global
#pragma unroll
    for (int tt = 0; tt < 2; ++tt) {
        float v = best[tt]; int id = bidx[tt];
#pragma unroll
        for (int m = 16; m <= 32; m <<= 1) {
            float ve = __shfl_xor(v, m, 64);
            int   ie = __shfl_xor(id, m, 64);
            if (ve < v || (ve == v && ie < id)) { v = ve; id = ie; }
        }
        if (lane < 16)
            partial[(size_t)q * 32768 + T0 + tt * 16 + lane] =
                make_float2(v, __int_as_float(id));
    }
}

// ---------------- kernel 3: combine 4 + gather + NCHW store + losses ----------
__global__ __launch_bounds__(256) void out_kernel(
    const float* __restrict__ W, const float2* __restrict__ partial,
    const float* __restrict__ xsq, float* __restrict__ dsum,
    unsigned int* __restrict__ counter, float* __restrict__ out)
{
    __shared__ float tile[256][65];
    __shared__ int lidx[64];
    __shared__ int elected;
    int t = threadIdx.x, g = blockIdx.x;
    int n0 = g * 64;
    int b = n0 >> 10, sb = n0 & 1023;

    if (t == 0) elected = 0;
    if (t < 64) {
        float2 p = partial[n0 + t];
        float v = p.x; int id = __float_as_int(p.y);
#pragma unroll
        for (int q = 1; q < 4; ++q) {
            float2 pq = partial[(size_t)q * 32768 + n0 + t];
            if (pq.x < v) { v = pq.x; id = __float_as_int(pq.y); }  // tie -> lower q
        }
        lidx[t] = id;
        float dmin = v;                              // min(-2x.w + ||w||^2) part
#pragma unroll
        for (int m = 1; m < 64; m <<= 1) dmin += __shfl_xor(dmin, m, 64);
        if (t == 0) {
            dsum[g] = dmin;                          // plain store, unique slot
            __threadfence();
            // poison-tolerant election: exactly one of 512 sees old % 512 == 511
            if ((atomicAdd(counter, 1u) & 511u) == 511u) elected = 1;
        }
    }
    __syncthreads();

    int tok = t >> 2, cq = t & 3;
    const float* wr = W + ((size_t)lidx[tok] << 8);
#pragma unroll
    for (int j = 0; j < 16; ++j) {
        int c = cq * 4 + j * 16;
        float4 v = *(const float4*)&wr[c];
        tile[c + 0][tok] = v.x; tile[c + 1][tok] = v.y;
        tile[c + 2][tok] = v.z; tile[c + 3][tok] = v.w;
    }
    __syncthreads();
    float* op = out + (((size_t)(b * 256 + t)) << 10) + sb;
#pragma unroll
    for (int j = 0; j < 16; ++j) {
        float4 v;
        v.x = tile[t][j * 4 + 0]; v.y = tile[t][j * 4 + 1];
        v.z = tile[t][j * 4 + 2]; v.w = tile[t][j * 4 + 3];
        *(float4*)&op[j * 4] = v;
    }

    if (elected && t < 64) {                         // wave-parallel finalize
        __threadfence();                             // acquire dsum/xsq stores
        float acc = 0.f;
        for (int i = t; i < 4096; i += 64) acc += xsq[i];
        for (int i = t; i < 512;  i += 64) acc += dsum[i];
#pragma unroll
        for (int m = 1; m < 64; m <<= 1) acc += __shfl_xor(acc, m, 64);
        if (t == 0) {
            float mse = acc * (1.0f / 8388608.0f);
            out[8388608] = 1.25f * mse;              // vq_loss
            out[8388609] = mse;                      // embedding_loss
            out[8388610] = mse;                      // commitment_loss
        }
    }
}

extern "C" void kernel_launch(void* const* d_in, const int* in_sizes, int n_in,
                              void* d_out, int out_size, void* d_ws, size_t ws_size,
                              hipStream_t stream)
{
    (void)in_sizes; (void)n_in; (void)out_size; (void)ws_size;
    const float* X = (const float*)d_in[0];   // [32,256,32,32] fp32
    const float* W = (const float*)d_in[1];   // [1024,256] fp32
    float* out = (float*)d_out;               // [8388608 out | vq | emb | commit]
    char* ws = (char*)d_ws;
    unsigned int*   counter = (unsigned int*)ws;                 // @0 (poison-tolerant)
    float*          cw      = (float*)(ws + 4096);               // 4KB
    unsigned short* wh      = (unsigned short*)(ws + 8192);      // 512KB (swizzled bf16)
    float*          xsq     = (float*)(ws + 1048576);            // 16KB (4096 slots)
    float*          dsum    = (float*)(ws + 1114112);            // 2KB  (512 slots)
    unsigned short* xt      = (unsigned short*)(ws + 2097152);   // 16.8MB (linear bf16)
    float2*         partial = (float2*)(ws + 19922944);          // 1MB (4 x 32768)

    prep_kernel<<<1088, 256, 0, stream>>>(W, X, wh, cw, xt, xsq);
    argmin_kernel<<<2048, 128, 0, stream>>>(wh, xt, cw, partial);
    out_kernel<<<512, 256, 0, stream>>>(W, partial, xsq, dsum, counter, out);
}

// Round 9
// 74.132 us; speedup vs baseline: 2.4565x; 1.1485x over previous
//
#include <hip/hip_runtime.h>
#include <cfloat>

typedef short bf16x8 __attribute__((ext_vector_type(8)));
typedef float f32x4  __attribute__((ext_vector_type(4)));

static __device__ __forceinline__ void gl_lds16(const void* g, void* l) {
    __builtin_amdgcn_global_load_lds(
        (const __attribute__((address_space(1))) unsigned int*)g,
        (__attribute__((address_space(3))) unsigned int*)l, 16, 0, 0);
}

static __device__ __forceinline__ unsigned int pack2(float a, float b) {
    unsigned short ha = __builtin_bit_cast(unsigned short, (__bf16)a);
    unsigned short hb = __builtin_bit_cast(unsigned short, (__bf16)b);
    return (unsigned int)ha | ((unsigned int)hb << 16);
}

// ---------------- kernel 1: prep ----------------
// blocks 0..63    : W -> bf16 XOR-swizzled wh (16B granule ^ (row&7)) + ||w||^2
// blocks 64..1087 : X -> token-major bf16 LINEAR Xt (32-channel register batch
//                   for ILP, 64B contiguous store) + per-wave sum x^2 to a
//                   DISTINCT slot (non-atomic, rewritten every call)
__global__ __launch_bounds__(256) void prep_kernel(
    const float* __restrict__ W, const float* __restrict__ X,
    unsigned short* __restrict__ wh, float* __restrict__ cw,
    unsigned short* __restrict__ xt, float* __restrict__ xsq)
{
    int t = threadIdx.x, blk = blockIdx.x;
    if (blk < 64) {
        int row = blk * 16 + (t >> 4);
        int c0  = (t & 15) * 16;
        const float* wr = W + row * 256 + c0;
        float s = 0.f;
        unsigned int pk[8];
#pragma unroll
        for (int i = 0; i < 16; i += 2) {
            float a = wr[i], b = wr[i + 1];
            s += a * a + b * b;
            pk[i >> 1] = pack2(a, b);
        }
        int g0 = (t & 15) * 2, e = row & 7;        // swizzle for the LDS read path
        uint4* dst = (uint4*)&wh[row * 256];
        dst[g0 ^ e]       = make_uint4(pk[0], pk[1], pk[2], pk[3]);
        dst[(g0 + 1) ^ e] = make_uint4(pk[4], pk[5], pk[6], pk[7]);
#pragma unroll
        for (int m = 1; m < 16; m <<= 1) s += __shfl_xor(s, m, 64);
        if ((t & 15) == 0) cw[row] = s;
    } else {
        int bx = blk - 64;                          // 0..1023
        int er = bx >> 7;                           // channel-eighth, uniform per block
        int tok = (bx & 127) * 256 + t;             // lanes = consecutive tokens
        int b = tok >> 10, s = tok & 1023;
        const float* xp = X + ((size_t)b << 18) + s + ((size_t)(er * 32) << 10);

        float va[32];                               // all 32 loads in flight first
#pragma unroll
        for (int i = 0; i < 32; ++i) va[i] = xp[(size_t)i << 10];

        float acc = 0.f;
        unsigned int pk[16];
#pragma unroll
        for (int i = 0; i < 32; i += 2) {
            acc = fmaf(va[i], va[i], fmaf(va[i + 1], va[i + 1], acc));
            pk[i >> 1] = pack2(va[i], va[i + 1]);
        }
        uint4* dst = (uint4*)&xt[(size_t)tok * 256];
#pragma unroll
        for (int g = 0; g < 4; ++g)
            dst[er * 4 + g] = make_uint4(pk[g*4], pk[g*4+1], pk[g*4+2], pk[g*4+3]);

#pragma unroll
        for (int m = 1; m < 64; m <<= 1) acc += __shfl_xor(acc, m, 64);
        if ((t & 63) == 0) xsq[bx * 4 + (t >> 6)] = acc;   // unique slot, no atomic
    }
}

// ---------------- kernel 2: streamed distance-GEMM + per-quarter argmin -------
// grid 1024 = 256 token-subgroups (fast) x 4 code-quarters. Block 128thr
// (2 waves) + 2x16KB LDS dbuf -> 4 blocks/CU. Wave = 64 TOKENS (fx[4][8],
// 128 VGPR, asm-pinned): halves per-CU ds_read_b128 count and W L2-stream
// vs R8 (LDS pipe was the bottleneck: 1 LDS unit/CU vs 4 MFMA pipes).
// af loaded per-rt and epilogue per-rt to cap VGPR (~215 < 256).
__global__ __launch_bounds__(128, 2) void argmin_kernel(
    const unsigned short* __restrict__ wh, const unsigned short* __restrict__ xt,
    const float* __restrict__ cw, float2* __restrict__ partial)
{
    __shared__ __align__(16) unsigned short wlds[2][32 * 256];   // 2 x 16 KB
    int tid  = threadIdx.x;
    int lane = tid & 63, w = tid >> 6;              // 2 waves
    int sg = blockIdx.x & 255;                      // token subgroup (128 tokens)
    int q  = blockIdx.x >> 8;                       // code quarter (256 codes)
    int srow = lane & 15, kgrp = lane >> 4;

    const char* wq = (const char*)wh + (size_t)q * 256 * 512;
    int rsub = w * 2 + (lane >> 5);                 // row within a 4-row DMA round
    int gcol = lane & 31;                           // 16B granule within 512B row

    // stage chunk ch (32 codes x 512B = 16KB) into wlds[buf]
    auto stage = [&](int ch, int buf) {
        const char* src = wq + (size_t)(ch * 32 + rsub) * 512 + gcol * 16;
        char* dstb = (char*)&wlds[buf][0] + w * 1024;   // wave-uniform base
#pragma unroll
        for (int i = 0; i < 8; ++i)
            gl_lds16(src + i * 2048, dstb + i * 2048);
    };

    stage(0, 0);

    // X fragments: 32 x b128 in flight, then PINNED in registers
    int T0 = sg * 128 + w * 64;
    bf16x8 fx[4][8];
#pragma unroll
    for (int tt = 0; tt < 4; ++tt) {
        const unsigned short* xr = xt + (size_t)(T0 + tt * 16 + srow) * 256;
#pragma unroll
        for (int ks = 0; ks < 8; ++ks)
            fx[tt][ks] = *(const bf16x8*)&xr[(ks * 4 + kgrp) * 8];
    }
#pragma unroll
    for (int tt = 0; tt < 4; ++tt)
#pragma unroll
        for (int ks = 0; ks < 8; ++ks)
            asm volatile("" : "+v"(fx[tt][ks]));    // force register residency

    asm volatile("s_waitcnt vmcnt(0)" ::: "memory");
    __syncthreads();                                // chunk 0 + fx visible

    float best[4] = {FLT_MAX, FLT_MAX, FLT_MAX, FLT_MAX};
    int   bidx[4] = {0, 0, 0, 0};
    const float* cwq = cw + q * 256;
    int cur = 0;

    for (int ch = 0; ch < 8; ++ch) {
        if (ch < 7) stage(ch + 1, cur ^ 1);         // prefetch overlaps compute

#pragma unroll
        for (int rt = 0; rt < 2; ++rt) {
            int r = rt * 16 + srow, eb = r & 7;
            const unsigned short* ar = &wlds[cur][r * 256];
            bf16x8 af[8];
#pragma unroll
            for (int ks = 0; ks < 8; ++ks)
                af[ks] = *(const bf16x8*)&ar[((ks * 4 + kgrp) ^ eb) * 8];

            f32x4 acc[4];
#pragma unroll
            for (int tt = 0; tt < 4; ++tt) acc[tt] = (f32x4){0.f, 0.f, 0.f, 0.f};
#pragma unroll
            for (int ks = 0; ks < 8; ++ks)
#pragma unroll
                for (int tt = 0; tt < 4; ++tt)
                    acc[tt] = __builtin_amdgcn_mfma_f32_16x16x32_bf16(
                        af[ks], fx[tt][ks], acc[tt], 0, 0, 0);

            float4 cw4 = *(const float4*)&cwq[ch * 32 + rt * 16 + kgrp * 4];
            int cb = q * 256 + ch * 32 + rt * 16 + kgrp * 4;
#pragma unroll
            for (int j = 0; j < 4; ++j) {
                float cwv = j == 0 ? cw4.x : j == 1 ? cw4.y : j == 2 ? cw4.z : cw4.w;
#pragma unroll
                for (int tt = 0; tt < 4; ++tt) {
                    float e2 = fmaf(-2.f, acc[tt][j], cwv);
                    bool better = e2 < best[tt];     // strict <: lowest code wins
                    best[tt] = better ? e2 : best[tt];
                    bidx[tt] = better ? (cb + j) : bidx[tt];
                }
            }
        }

        asm volatile("s_waitcnt vmcnt(0)" ::: "memory");  // own next-chunk DMA done
        __syncthreads();                                  // all waves' DMA + reads done
        cur ^= 1;
    }

    // in-wave argmin over kgrp groups, then per-quarter partial to global
#pragma unroll
    for (int tt = 0; tt < 4; ++tt) {
        float v = best[tt]; int id = bidx[tt];
#pragma unroll
        for (int m = 16; m <= 32; m <<= 1) {
            float ve = __shfl_xor(v, m, 64);
            int   ie = __shfl_xor(id, m, 64);
            if (ve < v || (ve == v && ie < id)) { v = ve; id = ie; }
        }
        if (lane < 16)
            partial[(size_t)q * 32768 + T0 + tt * 16 + lane] =
                make_float2(v, __int_as_float(id));
    }
}

// ---------------- kernel 3: combine 4 + gather + NCHW store + losses ----------
// Store mapping fixed (R8 lesson: lane-stride-4KB stores ran at 11% HBM):
// lane = spatial -> each wave store = 4 channels x 256B contiguous runs.
__global__ __launch_bounds__(256) void out_kernel(
    const float* __restrict__ W, const float2* __restrict__ partial,
    const float* __restrict__ xsq, float* __restrict__ dsum,
    unsigned int* __restrict__ counter, float* __restrict__ out)
{
    __shared__ float tile[256][68];                  // 68: 16B-aligned b128 rows
    __shared__ int lidx[64];
    __shared__ int elected;
    int t = threadIdx.x, g = blockIdx.x;
    int n0 = g * 64;
    int b = n0 >> 10, sb = n0 & 1023;

    if (t == 0) elected = 0;
    if (t < 64) {
        float2 p = partial[n0 + t];
        float v = p.x; int id = __float_as_int(p.y);
#pragma unroll
        for (int q = 1; q < 4; ++q) {
            float2 pq = partial[(size_t)q * 32768 + n0 + t];
            if (pq.x < v) { v = pq.x; id = __float_as_int(pq.y); }  // tie -> lower q
        }
        lidx[t] = id;
        float dmin = v;                              // min(-2x.w + ||w||^2) part
#pragma unroll
        for (int m = 1; m < 64; m <<= 1) dmin += __shfl_xor(dmin, m, 64);
        if (t == 0) {
            dsum[g] = dmin;                          // plain store, unique slot
            __threadfence();
            // poison-tolerant election: exactly one of 512 sees old % 512 == 511
            if ((atomicAdd(counter, 1u) & 511u) == 511u) elected = 1;
        }
    }
    __syncthreads();

    int tok = t >> 2, cq = t & 3;
    const float* wr = W + ((size_t)lidx[tok] << 8);
#pragma unroll
    for (int j = 0; j < 16; ++j) {
        int c = cq * 4 + j * 16;
        float4 v = *(const float4*)&wr[c];
        tile[c + 0][tok] = v.x; tile[c + 1][tok] = v.y;
        tile[c + 2][tok] = v.z; tile[c + 3][tok] = v.w;
    }
    __syncthreads();

    int s4 = (t & 15) * 4;                           // lane -> spatial (coalesced)
#pragma unroll
    for (int j = 0; j < 16; ++j) {
        int c = (t >> 4) + j * 16;
        float4 v = *(const float4*)&tile[c][s4];
        *(float4*)&out[(((size_t)(b * 256 + c)) << 10) + sb + s4] = v;
    }

    if (elected && t < 64) {                         // wave-parallel finalize
        __threadfence();                             // acquire dsum/xsq stores
        float acc = 0.f;
        for (int i = t; i < 4096; i += 64) acc += xsq[i];
        for (int i = t; i < 512;  i += 64) acc += dsum[i];
#pragma unroll
        for (int m = 1; m < 64; m <<= 1) acc += __shfl_xor(acc, m, 64);
        if (t == 0) {
            float mse = acc * (1.0f / 8388608.0f);
            out[8388608] = 1.25f * mse;              // vq_loss
            out[8388609] = mse;                      // embedding_loss
            out[8388610] = mse;                      // commitment_loss
        }
    }
}

extern "C" void kernel_launch(void* const* d_in, const int* in_sizes, int n_in,
                              void* d_out, int out_size, void* d_ws, size_t ws_size,
                              hipStream_t stream)
{
    (void)in_sizes; (void)n_in; (void)out_size; (void)ws_size;
    const float* X = (const float*)d_in[0];   // [32,256,32,32] fp32
    const float* W = (const float*)d_in[1];   // [1024,256] fp32
    float* out = (float*)d_out;               // [8388608 out | vq | emb | commit]
    char* ws = (char*)d_ws;
    unsigned int*   counter = (unsigned int*)ws;                 // @0 (poison-tolerant)
    float*          cw      = (float*)(ws + 4096);               // 4KB
    unsigned short* wh      = (unsigned short*)(ws + 8192);      // 512KB (swizzled bf16)
    float*          xsq     = (float*)(ws + 1048576);            // 16KB (4096 slots)
    float*          dsum    = (float*)(ws + 1114112);            // 2KB  (512 slots)
    unsigned short* xt      = (unsigned short*)(ws + 2097152);   // 16.8MB (linear bf16)
    float2*         partial = (float2*)(ws + 19922944);          // 1MB (4 x 32768)

    prep_kernel<<<1088, 256, 0, stream>>>(W, X, wh, cw, xt, xsq);
    argmin_kernel<<<1024, 128, 0, stream>>>(wh, xt, cw, partial);
    out_kernel<<<512, 256, 0, stream>>>(W, partial, xsq, dsum, counter, out);
}

// Round 10
// 72.873 us; speedup vs baseline: 2.4990x; 1.0173x over previous
//
#include <hip/hip_runtime.h>
#include <cfloat>

typedef short bf16x8 __attribute__((ext_vector_type(8)));
typedef float f32x4  __attribute__((ext_vector_type(4)));

static __device__ __forceinline__ void gl_lds16(const void* g, void* l) {
    __builtin_amdgcn_global_load_lds(
        (const __attribute__((address_space(1))) unsigned int*)g,
        (__attribute__((address_space(3))) unsigned int*)l, 16, 0, 0);
}

static __device__ __forceinline__ unsigned int pack2(float a, float b) {
    unsigned short ha = __builtin_bit_cast(unsigned short, (__bf16)a);
    unsigned short hb = __builtin_bit_cast(unsigned short, (__bf16)b);
    return (unsigned int)ha | ((unsigned int)hb << 16);
}

// ---------------- kernel 1: prep ----------------
// blocks 0..63    : W -> bf16 XOR-swizzled wh (16B granule ^ (row&7)) + ||w||^2
// blocks 64..1087 : X -> token-major bf16 LINEAR Xt (32-channel register batch
//                   for ILP, 64B contiguous store) + per-wave sum x^2 to a
//                   DISTINCT slot (non-atomic, rewritten every call)
__global__ __launch_bounds__(256) void prep_kernel(
    const float* __restrict__ W, const float* __restrict__ X,
    unsigned short* __restrict__ wh, float* __restrict__ cw,
    unsigned short* __restrict__ xt, float* __restrict__ xsq)
{
    int t = threadIdx.x, blk = blockIdx.x;
    if (blk < 64) {
        int row = blk * 16 + (t >> 4);
        int c0  = (t & 15) * 16;
        const float* wr = W + row * 256 + c0;
        float s = 0.f;
        unsigned int pk[8];
#pragma unroll
        for (int i = 0; i < 16; i += 2) {
            float a = wr[i], b = wr[i + 1];
            s += a * a + b * b;
            pk[i >> 1] = pack2(a, b);
        }
        int g0 = (t & 15) * 2, e = row & 7;        // swizzle for the LDS read path
        uint4* dst = (uint4*)&wh[row * 256];
        dst[g0 ^ e]       = make_uint4(pk[0], pk[1], pk[2], pk[3]);
        dst[(g0 + 1) ^ e] = make_uint4(pk[4], pk[5], pk[6], pk[7]);
#pragma unroll
        for (int m = 1; m < 16; m <<= 1) s += __shfl_xor(s, m, 64);
        if ((t & 15) == 0) cw[row] = s;
    } else {
        int bx = blk - 64;                          // 0..1023
        int er = bx >> 7;                           // channel-eighth, uniform per block
        int tok = (bx & 127) * 256 + t;             // lanes = consecutive tokens
        int b = tok >> 10, s = tok & 1023;
        const float* xp = X + ((size_t)b << 18) + s + ((size_t)(er * 32) << 10);

        float va[32];                               // all 32 loads in flight first
#pragma unroll
        for (int i = 0; i < 32; ++i) va[i] = xp[(size_t)i << 10];

        float acc = 0.f;
        unsigned int pk[16];
#pragma unroll
        for (int i = 0; i < 32; i += 2) {
            acc = fmaf(va[i], va[i], fmaf(va[i + 1], va[i + 1], acc));
            pk[i >> 1] = pack2(va[i], va[i + 1]);
        }
        uint4* dst = (uint4*)&xt[(size_t)tok * 256];
#pragma unroll
        for (int g = 0; g < 4; ++g)
            dst[er * 4 + g] = make_uint4(pk[g*4], pk[g*4+1], pk[g*4+2], pk[g*4+3]);

#pragma unroll
        for (int m = 1; m < 64; m <<= 1) acc += __shfl_xor(acc, m, 64);
        if ((t & 63) == 0) xsq[bx * 4 + (t >> 6)] = acc;   // unique slot, no atomic
    }
}

// ---------------- kernel 2: W-stationary distance-GEMM + per-quarter argmin ----
// REVERT to the R5 structure (fastest measured: ~20us inferred): grid 256 =
// 64 token-groups x 4 code-quarters (q SLOW: same-sg quarters on same XCD for
// Xt L2 locality), block 512thr (8 waves), W quarter (256 codes, 128KB bf16)
// staged into LDS ONCE via global_load_lds, barrier-free 16-chunk main loop.
// Delta vs R5: fx asm-PINNED (cures R7-style remat; ~200 VGPR fits 256 budget).
__global__ __launch_bounds__(512, 2) void argmin_kernel(
    const unsigned short* __restrict__ wh, const unsigned short* __restrict__ xt,
    const float* __restrict__ cw, float2* __restrict__ partial)
{
    __shared__ unsigned short wlds[256 * 256];     // 128 KB
    int tid  = threadIdx.x;
    int lane = tid & 63, w = tid >> 6;
    int sg = blockIdx.x & 63, q = blockIdx.x >> 6; // q slow (64%8==0 -> same XCD)
    int srow = lane & 15, kgrp = lane >> 4;

    // stage W quarter once: wave w owns rows [w*32, w*32+32)  (16 x 1KB DMA)
    const char* wsrc = (const char*)wh + (size_t)(q * 256 + w * 32) * 512;
    char* wdst = (char*)wlds + w * 16384;
#pragma unroll
    for (int j = 0; j < 16; ++j)
        gl_lds16(wsrc + j * 1024 + lane * 16, wdst + j * 1024);

    // X fragments (overlap with W DMA), then PINNED in registers
    int T0 = sg * 512 + w * 64;
    bf16x8 fx[4][8];
#pragma unroll
    for (int tt = 0; tt < 4; ++tt) {
        const unsigned short* xr = xt + (size_t)(T0 + tt * 16 + srow) * 256;
#pragma unroll
        for (int ks = 0; ks < 8; ++ks)
            fx[tt][ks] = *(const bf16x8*)&xr[(ks * 4 + kgrp) * 8];
    }
#pragma unroll
    for (int tt = 0; tt < 4; ++tt)
#pragma unroll
        for (int ks = 0; ks < 8; ++ks)
            asm volatile("" : "+v"(fx[tt][ks]));   // force register residency

    asm volatile("s_waitcnt vmcnt(0)" ::: "memory");
    __syncthreads();                               // W quarter + fx visible

    float best[4] = {FLT_MAX, FLT_MAX, FLT_MAX, FLT_MAX};
    int   bidx[4] = {0, 0, 0, 0};
    const float* cwq = cw + q * 256;

    for (int ch = 0; ch < 16; ++ch) {
        int r = ch * 16 + srow, eb = r & 7;
        const unsigned short* ar = &wlds[r * 256];
        bf16x8 af[8];
#pragma unroll
        for (int ks = 0; ks < 8; ++ks)
            af[ks] = *(const bf16x8*)&ar[((ks * 4 + kgrp) ^ eb) * 8];

        float4 cw4 = *(const float4*)&cwq[ch * 16 + kgrp * 4];

        f32x4 acc[4];
#pragma unroll
        for (int tt = 0; tt < 4; ++tt) acc[tt] = (f32x4){0.f, 0.f, 0.f, 0.f};
#pragma unroll
        for (int ks = 0; ks < 8; ++ks)
#pragma unroll
            for (int tt = 0; tt < 4; ++tt)
                acc[tt] = __builtin_amdgcn_mfma_f32_16x16x32_bf16(
                    af[ks], fx[tt][ks], acc[tt], 0, 0, 0);

        int cb = q * 256 + ch * 16 + kgrp * 4;
#pragma unroll
        for (int j = 0; j < 4; ++j) {
            float cwv = j == 0 ? cw4.x : j == 1 ? cw4.y : j == 2 ? cw4.z : cw4.w;
#pragma unroll
            for (int tt = 0; tt < 4; ++tt) {
                float e2 = fmaf(-2.f, acc[tt][j], cwv);
                bool better = e2 < best[tt];       // strict <: lowest code wins
                best[tt] = better ? e2 : best[tt];
                bidx[tt] = better ? (cb + j) : bidx[tt];
            }
        }
    }

    // in-wave argmin over kgrp groups, then per-quarter partial to global
#pragma unroll
    for (int tt = 0; tt < 4; ++tt) {
        float v = best[tt]; int id = bidx[tt];
#pragma unroll
        for (int m = 16; m <= 32; m <<= 1) {
            float ve = __shfl_xor(v, m, 64);
            int   ie = __shfl_xor(id, m, 64);
            if (ve < v || (ve == v && ie < id)) { v = ve; id = ie; }
        }
        if (lane < 16)
            partial[(size_t)q * 32768 + T0 + tt * 16 + lane] =
                make_float2(v, __int_as_float(id));
    }
}

// ---------------- kernel 3: combine 4 + gather + NCHW store + losses ----------
// lane = spatial on the store side: each wave store = 4 channels x 256B runs.
__global__ __launch_bounds__(256) void out_kernel(
    const float* __restrict__ W, const float2* __restrict__ partial,
    const float* __restrict__ xsq, float* __restrict__ dsum,
    unsigned int* __restrict__ counter, float* __restrict__ out)
{
    __shared__ float tile[256][68];                  // 16B-aligned b128 rows
    __shared__ int lidx[64];
    __shared__ int elected;
    int t = threadIdx.x, g = blockIdx.x;
    int n0 = g * 64;
    int b = n0 >> 10, sb = n0 & 1023;

    if (t == 0) elected = 0;
    if (t < 64) {
        float2 p = partial[n0 + t];
        float v = p.x; int id = __float_as_int(p.y);
#pragma unroll
        for (int q = 1; q < 4; ++q) {
            float2 pq = partial[(size_t)q * 32768 + n0 + t];
            if (pq.x < v) { v = pq.x; id = __float_as_int(pq.y); }  // tie -> lower q
        }
        lidx[t] = id;
        float dmin = v;                              // min(-2x.w + ||w||^2) part
#pragma unroll
        for (int m = 1; m < 64; m <<= 1) dmin += __shfl_xor(dmin, m, 64);
        if (t == 0) {
            dsum[g] = dmin;                          // plain store, unique slot
            __threadfence();
            // poison-tolerant election: exactly one of 512 sees old % 512 == 511
            if ((atomicAdd(counter, 1u) & 511u) == 511u) elected = 1;
        }
    }
    __syncthreads();

    int tok = t >> 2, cq = t & 3;
    const float* wr = W + ((size_t)lidx[tok] << 8);
#pragma unroll
    for (int j = 0; j < 16; ++j) {
        int c = cq * 4 + j * 16;
        float4 v = *(const float4*)&wr[c];
        tile[c + 0][tok] = v.x; tile[c + 1][tok] = v.y;
        tile[c + 2][tok] = v.z; tile[c + 3][tok] = v.w;
    }
    __syncthreads();

    int s4 = (t & 15) * 4;                           // lane -> spatial (coalesced)
#pragma unroll
    for (int j = 0; j < 16; ++j) {
        int c = (t >> 4) + j * 16;
        float4 v = *(const float4*)&tile[c][s4];
        *(float4*)&out[(((size_t)(b * 256 + c)) << 10) + sb + s4] = v;
    }

    if (elected && t < 64) {                         // wave-parallel finalize
        __threadfence();                             // acquire dsum/xsq stores
        float acc = 0.f;
        for (int i = t; i < 4096; i += 64) acc += xsq[i];
        for (int i = t; i < 512;  i += 64) acc += dsum[i];
#pragma unroll
        for (int m = 1; m < 64; m <<= 1) acc += __shfl_xor(acc, m, 64);
        if (t == 0) {
            float mse = acc * (1.0f / 8388608.0f);
            out[8388608] = 1.25f * mse;              // vq_loss
            out[8388609] = mse;                      // embedding_loss
            out[8388610] = mse;                      // commitment_loss
        }
    }
}

extern "C" void kernel_launch(void* const* d_in, const int* in_sizes, int n_in,
                              void* d_out, int out_size, void* d_ws, size_t ws_size,
                              hipStream_t stream)
{
    (void)in_sizes; (void)n_in; (void)out_size; (void)ws_size;
    const float* X = (const float*)d_in[0];   // [32,256,32,32] fp32
    const float* W = (const float*)d_in[1];   // [1024,256] fp32
    float* out = (float*)d_out;               // [8388608 out | vq | emb | commit]
    char* ws = (char*)d_ws;
    unsigned int*   counter = (unsigned int*)ws;                 // @0 (poison-tolerant)
    float*          cw      = (float*)(ws + 4096);               // 4KB
    unsigned short* wh      = (unsigned short*)(ws + 8192);      // 512KB (swizzled bf16)
    float*          xsq     = (float*)(ws + 1048576);            // 16KB (4096 slots)
    float*          dsum    = (float*)(ws + 1114112);            // 2KB  (512 slots)
    unsigned short* xt      = (unsigned short*)(ws + 2097152);   // 16.8MB (linear bf16)
    float2*         partial = (float2*)(ws + 19922944);          // 1MB (4 x 32768)

    prep_kernel<<<1088, 256, 0, stream>>>(W, X, wh, cw, xt, xsq);
    argmin_kernel<<<256, 512, 0, stream>>>(wh, xt, cw, partial);
    out_kernel<<<512, 256, 0, stream>>>(W, partial, xsq, dsum, counter, out);
}